// Round 3
// baseline (274.192 us; speedup 1.0000x reference)
//
#include <hip/hip_runtime.h>

#define B_SZ    16
#define T_LEN   1024
#define C_CH    32
#define TC      (T_LEN * C_CH)      // 32768
#define S_MAIN  128
#define NB_P    400
#define P_TOP   60
#define OUT_CH  (NB_P + P_TOP)      // 460

typedef float        v4f __attribute__((ext_vector_type(4)));
typedef int          v4i __attribute__((ext_vector_type(4)));
typedef unsigned int v4u __attribute__((ext_vector_type(4)));

__device__ __forceinline__ unsigned short f32_to_bf16_rne(float f) {
    unsigned int u = __float_as_uint(f);
    unsigned int r = u + 0x7fffu + ((u >> 16) & 1u);
    return (unsigned short)(r >> 16);
}

// ---------------------------------------------------------------------------
// Kernel 1: transpose+pack x [B, T*C] f32 -> xb [T*C, 16] bf16.
// One index = 32 B (16 batches x bf16) = 2 lanes' worth of 16 B gathers.
// Thread i handles index i: 16 coalesced reads, one 32 B coalesced write.
// ---------------------------------------------------------------------------
__global__ __launch_bounds__(256) void transpose_pack(const float* __restrict__ x,
                                                      unsigned int* __restrict__ xb) {
    const int i = blockIdx.x * 256 + threadIdx.x;    // [0, TC)
    unsigned int u[8];
    #pragma unroll
    for (int k = 0; k < 8; ++k) {
        float v0 = __builtin_nontemporal_load(x + (size_t)(2 * k)     * TC + i);
        float v1 = __builtin_nontemporal_load(x + (size_t)(2 * k + 1) * TC + i);
        u[k] = (unsigned int)f32_to_bf16_rne(v0) |
               ((unsigned int)f32_to_bf16_rne(v1) << 16);
    }
    v4u a = { u[0], u[1], u[2], u[3] };
    v4u b = { u[4], u[5], u[6], u[7] };
    v4u* out = (v4u*)xb;
    out[(size_t)i * 2]     = a;   // batches 0..7
    out[(size_t)i * 2 + 1] = b;   // batches 8..15
}

// ---------------------------------------------------------------------------
// Patch compute v3: one wave per 4 pairs, bf16 gathers.
// Per gather instruction: lane = j*2+bh, j in [0,32) = k-index, bh = batch half.
// Each lane reads 16 B (8 bf16 batches) -> 256 scattered reqs/pair (was 512).
// idx/W staged via nt loads into wave-private LDS (keeps xb hot in L2).
// ---------------------------------------------------------------------------
template <int NPAIR_P, int NROWS, bool TO_WS>
__global__ __launch_bounds__(256, 4) void patch_v3(
    const v4u*   __restrict__ xb4,    // [TC*2] 16B blocks
    const int*   __restrict__ idx,    // [NROWS*NPAIR_P, 128]
    const float* __restrict__ W,      // [NROWS*NPAIR_P, 128]
    const float* __restrict__ bias,   // [NROWS*NPAIR_P]
    float*       __restrict__ dst)    // ws [B,NROWS,NPAIR_P] or out [B,T,460]
{
    __shared__ int   s_idx[16][128];
    __shared__ float s_w[16][128];
    const int wave = threadIdx.x >> 6;
    const int lane = threadIdx.x & 63;
    const int pairBase = blockIdx.x * 16 + wave * 4;

    // Stage idx+W for this wave's 4 pairs (wave-private LDS rows, no barrier).
    #pragma unroll
    for (int q = 0; q < 4; ++q) {
        const int pr = pairBase + q;
        if (lane < 32) {
            v4i t = __builtin_nontemporal_load((const v4i*)idx + (size_t)pr * 32 + lane);
            *(v4i*)&s_idx[wave * 4 + q][lane * 4] = t;
        } else {
            v4f t = __builtin_nontemporal_load((const v4f*)W + (size_t)pr * 32 + (lane - 32));
            *(v4f*)&s_w[wave * 4 + q][(lane - 32) * 4] = t;
        }
    }

    const int j  = lane >> 1;    // k-index within 32-chunk
    const int bh = lane & 1;     // batch half (8 batches = 16 B)

    float acc[4][8];
    #pragma unroll
    for (int q = 0; q < 4; ++q)
        #pragma unroll
        for (int k = 0; k < 8; ++k) acc[q][k] = 0.f;

    float bv[4];

    #pragma unroll
    for (int q = 0; q < 4; ++q) {
        bv[q] = bias[pairBase + q];
        #pragma unroll
        for (int g = 0; g < 4; ++g) {
            const int   ix = s_idx[wave * 4 + q][g * 32 + j];
            const float wt = s_w [wave * 4 + q][g * 32 + j];
            const v4u gv = xb4[(size_t)ix * 2 + bh];
            acc[q][0] += __uint_as_float(gv.x << 16)          * wt;
            acc[q][1] += __uint_as_float(gv.x & 0xffff0000u)  * wt;
            acc[q][2] += __uint_as_float(gv.y << 16)          * wt;
            acc[q][3] += __uint_as_float(gv.y & 0xffff0000u)  * wt;
            acc[q][4] += __uint_as_float(gv.z << 16)          * wt;
            acc[q][5] += __uint_as_float(gv.z & 0xffff0000u)  * wt;
            acc[q][6] += __uint_as_float(gv.w << 16)          * wt;
            acc[q][7] += __uint_as_float(gv.w & 0xffff0000u)  * wt;
        }
    }

    // Butterfly-reduce over j (lanes sharing bh); bit0 (bh) preserved.
    #pragma unroll
    for (int q = 0; q < 4; ++q)
        #pragma unroll
        for (int m = 2; m <= 32; m <<= 1)
            #pragma unroll
            for (int k = 0; k < 8; ++k)
                acc[q][k] += __shfl_xor(acc[q][k], m);

    if (j == 0) {   // lanes 0 (batches 0-7) and 1 (batches 8-15)
        #pragma unroll
        for (int q = 0; q < 4; ++q) {
            const int pr  = pairBase + q;
            const int row = pr / NPAIR_P;
            const int p   = pr - row * NPAIR_P;
            #pragma unroll
            for (int k = 0; k < 8; ++k) {
                const int b = bh * 8 + k;
                float val = acc[q][k] + bv[q];
                val = (val > 0.f) ? val : 0.3f * val;
                if (TO_WS) {
                    dst[((size_t)b * NROWS + row) * NPAIR_P + p] = val;
                } else {
                    __builtin_nontemporal_store(
                        val, &dst[((size_t)b * T_LEN + row) * OUT_CH + NB_P + p]);
                }
            }
        }
    }
}

// ---------------------------------------------------------------------------
// Upsample main result x8 along time into the output (coalesced).
// out row = 460 floats = 115 float4; main part = first 100 float4.
// ---------------------------------------------------------------------------
__global__ __launch_bounds__(256) void upsample_main(const float* __restrict__ ws_main,
                                                     float* __restrict__ out) {
    const int o4 = blockIdx.x * 256 + threadIdx.x;   // < B*T*100 = 1,638,400
    const int row = o4 / 100;
    const int col = o4 - row * 100;
    const int b = row >> 10;         // /1024
    const int t = row & 1023;
    const int s = t >> 3;            // /STRETCH
    const v4f v = ((const v4f*)ws_main)[((size_t)b * S_MAIN + s) * 100 + col];
    __builtin_nontemporal_store(v, &((v4f*)out)[(size_t)row * 115 + col]);
}

// ---------------------------------------------------------------------------
extern "C" void kernel_launch(void* const* d_in, const int* in_sizes, int n_in,
                              void* d_out, int out_size, void* d_ws, size_t ws_size,
                              hipStream_t stream) {
    const float* x      = (const float*)d_in[0];
    const float* W_main = (const float*)d_in[1];
    const float* b_main = (const float*)d_in[2];
    const float* W_top  = (const float*)d_in[3];
    const float* b_top  = (const float*)d_in[4];
    const int*  idx_main = (const int*)d_in[5];
    const int*  idx_top  = (const int*)d_in[6];
    float* out = (float*)d_out;

    unsigned int* xb   = (unsigned int*)d_ws;                        // 1 MB
    float* ws_main     = (float*)((char*)d_ws + (size_t)TC * 16 * 2);// 3.3 MB

    transpose_pack<<<TC / 256, 256, 0, stream>>>(x, xb);

    patch_v3<NB_P, S_MAIN, true>
        <<<(S_MAIN * NB_P) / 16, 256, 0, stream>>>((const v4u*)xb, idx_main, W_main, b_main, ws_main);

    patch_v3<P_TOP, T_LEN, false>
        <<<(T_LEN * P_TOP) / 16, 256, 0, stream>>>((const v4u*)xb, idx_top, W_top, b_top, out);

    upsample_main<<<(B_SZ * T_LEN * 100) / 256, 256, 0, stream>>>(ws_main, out);
}

// Round 4
// 252.564 us; speedup vs baseline: 1.0856x; 1.0856x over previous
//
#include <hip/hip_runtime.h>

#define B_SZ    16
#define T_LEN   1024
#define C_CH    32
#define TC      (T_LEN * C_CH)      // 32768
#define S_MAIN  128
#define NB_P    400
#define P_TOP   60
#define OUT_CH  (NB_P + P_TOP)      // 460
#define NGROUP  8                   // 8 groups x 2 batches

typedef float        v4f __attribute__((ext_vector_type(4)));
typedef unsigned int v4u __attribute__((ext_vector_type(4)));

__device__ __forceinline__ unsigned short f32_to_bf16_rne(float f) {
    unsigned int u = __float_as_uint(f);
    unsigned int r = u + 0x7fffu + ((u >> 16) & 1u);
    return (unsigned short)(r >> 16);
}

// ---------------------------------------------------------------------------
// Kernel 1: pack x [B, T*C] f32 -> 8 slices xs[g][T*C], each uint =
// bf16(x[2g][i]) | bf16(x[2g+1][i])<<16.  (LDS-gather-friendly layout.)
// ---------------------------------------------------------------------------
__global__ __launch_bounds__(256) void transpose_pack(const float* __restrict__ x,
                                                      unsigned int* __restrict__ xs) {
    const int i = blockIdx.x * 256 + threadIdx.x;    // [0, TC)
    #pragma unroll
    for (int g = 0; g < NGROUP; ++g) {
        float v0 = x[(size_t)(2 * g)     * TC + i];
        float v1 = x[(size_t)(2 * g + 1) * TC + i];
        unsigned int u = (unsigned int)f32_to_bf16_rne(v0) |
                         ((unsigned int)f32_to_bf16_rne(v1) << 16);
        xs[(size_t)g * TC + i] = u;
    }
}

// ---------------------------------------------------------------------------
// Patch compute v4: gather from LDS.
// Block = 1024 threads, owns (chunk c, batch-group g); 128 KB LDS slice.
// Swizzle: blockIdx%8 == c%8 so a chunk's 8 group-blocks share one XCD
// (its L2 serves the 8 reads of the chunk's idx/W stream).
// Wave: lane = j*4+q; q=pair-in-quad, j=0..15 handles 8 k-indices.
// Per pair: 2 ds_read_b32 per lane-slot -> 64 random gathers per instr.
// ---------------------------------------------------------------------------
__device__ __forceinline__ float leaky(float v) {
    return (v > 0.f) ? v : 0.3f * v;
}

template <int NPAIR_P, int NROWS, int NCHUNK, bool TO_WS>
__global__ __launch_bounds__(1024, 1) void patch_lds(
    const unsigned int* __restrict__ xs,   // [8][TC]
    const int*   __restrict__ idx,         // [NROWS*NPAIR_P, 128]
    const float* __restrict__ W,           // [NROWS*NPAIR_P, 128]
    const float* __restrict__ bias,        // [NROWS*NPAIR_P]
    float*       __restrict__ dst)         // ws [16,NROWS,NPAIR_P] or out [16,T,460]
{
    __shared__ unsigned int s_x[TC];       // 128 KB (gfx950: 160 KB/WG ok)
    constexpr int NPAIRS = NPAIR_P * NROWS;
    constexpr int CHUNK  = NPAIRS / NCHUNK;

    // Decode swizzled block id: b = (c%8) + 8*((c/8)*8 + g)
    const int bI = blockIdx.x;
    const int r  = bI >> 3;
    const int g  = r & 7;
    const int c  = (bI & 7) + 8 * (r >> 3);

    // Fill LDS slice (coalesced, 16 B per lane x 8)
    {
        const v4u* src = (const v4u*)(xs + (size_t)g * TC);
        v4u* dl = (v4u*)s_x;
        const int t = threadIdx.x;
        #pragma unroll
        for (int k = 0; k < 8; ++k)
            dl[k * 1024 + t] = src[k * 1024 + t];
    }
    __syncthreads();

    const int wave = threadIdx.x >> 6;     // 0..15
    const int lane = threadIdx.x & 63;
    const int q    = lane & 3;
    const int j    = lane >> 2;            // 0..15

    const int pair_lo = c * CHUNK;
    const int pair_hi = pair_lo + CHUNK;

    for (int p0 = pair_lo + wave * 4; p0 < pair_hi; p0 += 64) {
        const int pair = p0 + q;           // CHUNK % 4 == 0 -> in range

        const int4*   i4 = (const int4*)(idx + (size_t)pair * 128 + j * 8);
        const v4f*    w4 = (const v4f*)  (W   + (size_t)pair * 128 + j * 8);
        const int4 ia = i4[0];
        const int4 ib = i4[1];
        const v4f  wa = w4[0];
        const v4f  wb = w4[1];

        float a0 = 0.f, a1 = 0.f;
        #define GATHER(IX, WT)                                        \
            { unsigned int gv = s_x[(IX)];                            \
              a0 += __uint_as_float(gv << 16)         * (WT);         \
              a1 += __uint_as_float(gv & 0xffff0000u) * (WT); }
        GATHER(ia.x, wa.x) GATHER(ia.y, wa.y) GATHER(ia.z, wa.z) GATHER(ia.w, wa.w)
        GATHER(ib.x, wb.x) GATHER(ib.y, wb.y) GATHER(ib.z, wb.z) GATHER(ib.w, wb.w)
        #undef GATHER

        // Reduce over j (lanes sharing q): masks 4,8,16,32
        #pragma unroll
        for (int m = 4; m <= 32; m <<= 1) {
            a0 += __shfl_xor(a0, m);
            a1 += __shfl_xor(a1, m);
        }

        if (j == 0) {                       // lanes 0..3 hold pairs p0..p0+3
            const float bv = bias[pair];
            const int row = pair / NPAIR_P;
            const int p   = pair - row * NPAIR_P;
            const float v0 = leaky(a0 + bv);
            const float v1 = leaky(a1 + bv);
            const int b0 = 2 * g, b1 = 2 * g + 1;
            if (TO_WS) {
                dst[((size_t)b0 * NROWS + row) * NPAIR_P + p] = v0;
                dst[((size_t)b1 * NROWS + row) * NPAIR_P + p] = v1;
            } else {
                dst[((size_t)b0 * T_LEN + row) * OUT_CH + NB_P + p] = v0;
                dst[((size_t)b1 * T_LEN + row) * OUT_CH + NB_P + p] = v1;
            }
        }
    }
}

// ---------------------------------------------------------------------------
// Upsample main result x8 along time into the output (coalesced).
// out row = 460 floats = 115 float4; main part = first 100 float4.
// ---------------------------------------------------------------------------
__global__ __launch_bounds__(256) void upsample_main(const float* __restrict__ ws_main,
                                                     float* __restrict__ out) {
    const int o4 = blockIdx.x * 256 + threadIdx.x;   // < B*T*100 = 1,638,400
    const int row = o4 / 100;
    const int col = o4 - row * 100;
    const int b = row >> 10;         // /1024
    const int t = row & 1023;
    const int s = t >> 3;            // /STRETCH
    const v4f v = ((const v4f*)ws_main)[((size_t)b * S_MAIN + s) * 100 + col];
    ((v4f*)out)[(size_t)row * 115 + col] = v;
}

// ---------------------------------------------------------------------------
extern "C" void kernel_launch(void* const* d_in, const int* in_sizes, int n_in,
                              void* d_out, int out_size, void* d_ws, size_t ws_size,
                              hipStream_t stream) {
    const float* x      = (const float*)d_in[0];
    const float* W_main = (const float*)d_in[1];
    const float* b_main = (const float*)d_in[2];
    const float* W_top  = (const float*)d_in[3];
    const float* b_top  = (const float*)d_in[4];
    const int*  idx_main = (const int*)d_in[5];
    const int*  idx_top  = (const int*)d_in[6];
    float* out = (float*)d_out;

    unsigned int* xs  = (unsigned int*)d_ws;                          // 1 MB
    float* ws_main    = (float*)((char*)d_ws + (size_t)NGROUP * TC * 4);

    transpose_pack<<<TC / 256, 256, 0, stream>>>(x, xs);

    // main: 51200 pairs, 64 chunks x 800 pairs, x8 groups = 512 blocks
    patch_lds<NB_P, S_MAIN, 64, true>
        <<<64 * NGROUP, 1024, 0, stream>>>(xs, idx_main, W_main, b_main, ws_main);

    // top: 61440 pairs, 64 chunks x 960 pairs, x8 groups = 512 blocks
    patch_lds<P_TOP, T_LEN, 64, false>
        <<<64 * NGROUP, 1024, 0, stream>>>(xs, idx_top, W_top, b_top, out);

    upsample_main<<<(B_SZ * T_LEN * 100) / 256, 256, 0, stream>>>(ws_main, out);
}